// Round 8
// baseline (228.979 us; speedup 1.0000x reference)
//
#include <hip/hip_runtime.h>
#include <hip/hip_bf16.h>

#define TT 512
#define HH 1024
#define EE 32
#define KK 4
#define II 512
#define SS 2048

using f32x4 = __attribute__((ext_vector_type(4))) float;
using s16x8 = __attribute__((ext_vector_type(8))) short;

__device__ __forceinline__ unsigned short f2bf(float f){
  unsigned int u = __builtin_bit_cast(unsigned int, f);
  u += 0x7fffu + ((u >> 16) & 1u);
  return (unsigned short)(u >> 16);
}

// ---------------- router: logits, top-4, weights, sigmoid gate, x->bf16 -----
__global__ __launch_bounds__(64) void k_router(
    const float* __restrict__ x, const float* __restrict__ Wg,
    unsigned short* __restrict__ xb, int* __restrict__ topk_idx,
    float* __restrict__ topk_w, float* __restrict__ sig_gate){
  int t = blockIdx.x; int l = threadIdx.x;
  const float* xr = x + (size_t)t * HH;
  #pragma unroll
  for(int i=0;i<HH/64;i++){
    int h = l + 64*i;
    xb[(size_t)t*HH + h] = f2bf(xr[h]);
  }
  float acc0=0.f, acc1=0.f, acc2=0.f, acc3=0.f;
  if(l < EE+1){
    const float* wcol = Wg + l;
    for(int h=0; h<HH; h+=4){
      acc0 += xr[h]   * wcol[(size_t)h*(EE+1)];
      acc1 += xr[h+1] * wcol[(size_t)(h+1)*(EE+1)];
      acc2 += xr[h+2] * wcol[(size_t)(h+2)*(EE+1)];
      acc3 += xr[h+3] * wcol[(size_t)(h+3)*(EE+1)];
    }
  }
  __shared__ float lg[EE+1];
  if(l < EE+1) lg[l] = (acc0+acc1)+(acc2+acc3);
  __syncthreads();
  if(l == 0){
    float v[EE];
    #pragma unroll
    for(int i=0;i<EE;i++) v[i]=lg[i];
    int idx[KK]; float val[KK];
    #pragma unroll
    for(int k=0;k<KK;k++){
      float m=-1e30f; int mi=0;
      for(int i=0;i<EE;i++){ if(v[i]>m){ m=v[i]; mi=i; } }
      idx[k]=mi; val[k]=m; v[mi]=-1e30f;
    }
    float mx = val[0], s=0.f; float w[KK];
    #pragma unroll
    for(int k=0;k<KK;k++){ w[k]=__expf(val[k]-mx); s+=w[k]; }
    float inv = 1.f/s;
    #pragma unroll
    for(int k=0;k<KK;k++){ topk_idx[t*KK+k]=idx[k]; topk_w[t*KK+k]=w[k]*inv; }
    sig_gate[t] = 1.f/(1.f+__expf(-lg[EE]));
  }
}

// ---------------- per-expert token list (deterministic compaction) ----------
__global__ __launch_bounds__(64) void k_build(
    const int* __restrict__ topk_idx, const float* __restrict__ topk_w,
    int* __restrict__ token_list, float* __restrict__ weight_list,
    int* __restrict__ counts){
  int e = blockIdx.x; int l = threadIdx.x;
  int cnt = 0;
  for(int c=0;c<TT;c+=64){
    int t = c + l;
    int kk = -1;
    #pragma unroll
    for(int k=0;k<KK;k++) if(topk_idx[t*KK+k]==e) kk=k;
    unsigned long long b = __ballot(kk>=0);
    int pre = __popcll(b & ((1ull<<l)-1ull));
    if(kk>=0){
      token_list[e*TT + cnt + pre] = t;
      weight_list[e*TT + cnt + pre] = topk_w[t*KK+kk];
    }
    cnt += __popcll(b);
  }
  if(l==0) counts[e]=cnt;
}

__global__ __launch_bounds__(64) void k_scan(
    const int* __restrict__ counts, int* __restrict__ offs){
  if(threadIdx.x==0){
    int o=0;
    for(int e=0;e<EE;e++){ offs[e]=o; o+=counts[e]; }
  }
}

// ---------- convert fp32 [nmat][K][N] -> bf16 k8-packed [nmat][K/8][N][8] ----
// grid (N/256, K/8, nmat), block 256. Coalesced read rows, coalesced write.
__global__ __launch_bounds__(256) void k_convert(
    const float* __restrict__ src, unsigned short* __restrict__ dst,
    int K, int N){
  int nm = blockIdx.z;
  const float* S = src + (size_t)nm*K*N;
  unsigned short* D = dst + (size_t)nm*K*N;
  int k0 = blockIdx.y*8, n0 = blockIdx.x*256;
  __shared__ float tile[8][260];
  int t = threadIdx.x;
  int row = t>>5, c8 = (t&31)*8;
  const float* p = S + (size_t)(k0+row)*N + n0 + c8;
  float4 v0 = *reinterpret_cast<const float4*>(p);
  float4 v1 = *reinterpret_cast<const float4*>(p+4);
  *reinterpret_cast<float4*>(&tile[row][c8])   = v0;
  *reinterpret_cast<float4*>(&tile[row][c8+4]) = v1;
  __syncthreads();
  unsigned short u[8];
  #pragma unroll
  for(int r=0;r<8;r++) u[r] = f2bf(tile[r][t]);
  uint4 o;
  o.x = (unsigned)u[0] | ((unsigned)u[1]<<16);
  o.y = (unsigned)u[2] | ((unsigned)u[3]<<16);
  o.z = (unsigned)u[4] | ((unsigned)u[5]<<16);
  o.w = (unsigned)u[6] | ((unsigned)u[7]<<16);
  *reinterpret_cast<uint4*>(D + ((size_t)(k0>>3)*N + n0 + t)*8) = o;
}

// ============ register-direct GEMM core (no LDS, no barriers) ===============
// Wave computes 16 rows x 64 cols. Per K-step(32): 1 A-load + 4 B-loads/mat,
// all 16 B contiguous per lane (k8-packed B; row-major bf16 A). Depth-2.
// Fragment mapping (verified r89): frag row/col = lane&15, k = (lane>>4)*8+j;
// C/D: col = lane&15, row = (lane>>4)*4 + j.

#define LD16(p) (*reinterpret_cast<const uint4*>(p))
__device__ __forceinline__ s16x8 cvt16(uint4 v){ return __builtin_bit_cast(s16x8, v); }

// DUAL gate+up body. Ap: per-lane A ptr (advances 32 elems/step).
// Gp/Up: per-lane B ptr at (q, col) (advances 32*N elems/step). Imm c*256 B.
template<bool DUAL>
__device__ __forceinline__ void gemm_rd(
    const unsigned short* __restrict__ Ap,
    const unsigned short* __restrict__ Gp,
    const unsigned short* __restrict__ Up,
    int N, int NK, f32x4* ag, f32x4* au){
  uint4 a0, g0[4], u0[4], a1, g1[4], u1[4];
  a0 = LD16(Ap);
  #pragma unroll
  for(int c=0;c<4;c++){
    g0[c] = LD16(Gp + c*128);
    if(DUAL) u0[c] = LD16(Up + c*128);
  }
  for(int ks=0; ks<NK; ks++){
    const bool more = (ks+1 < NK);
    if(more){
      a1 = LD16(Ap + (size_t)(ks+1)*32);
      const unsigned short* gp = Gp + (size_t)(ks+1)*32*N;
      #pragma unroll
      for(int c=0;c<4;c++) g1[c] = LD16(gp + c*128);
      if(DUAL){
        const unsigned short* up = Up + (size_t)(ks+1)*32*N;
        #pragma unroll
        for(int c=0;c<4;c++) u1[c] = LD16(up + c*128);
      }
    }
    s16x8 af = cvt16(a0);
    #pragma unroll
    for(int c=0;c<4;c++){
      ag[c] = __builtin_amdgcn_mfma_f32_16x16x32_bf16(af, cvt16(g0[c]), ag[c], 0,0,0);
      if(DUAL)
        au[c] = __builtin_amdgcn_mfma_f32_16x16x32_bf16(af, cvt16(u0[c]), au[c], 0,0,0);
    }
    a0 = a1;
    #pragma unroll
    for(int c=0;c<4;c++){ g0[c]=g1[c]; if(DUAL) u0[c]=u1[c]; }
  }
}

// ---------------- phase 2: ALL gate-up (shared + routed) --------------------
__global__ __launch_bounds__(256) void k_gateup(
    const unsigned short* __restrict__ xb,
    const unsigned short* __restrict__ Bsg, const unsigned short* __restrict__ Bsu,
    unsigned short* __restrict__ Hs,
    const unsigned short* __restrict__ Bgate, const unsigned short* __restrict__ Bup,
    const int* __restrict__ token_list, const int* __restrict__ counts,
    const int* __restrict__ offs, unsigned short* __restrict__ hbuf){
  int tid = threadIdx.x, w = tid>>6, l = tid&63;
  int n16 = l&15, q = l>>4;
  int bid = blockIdx.x;
  f32x4 zero = {0.f,0.f,0.f,0.f};
  const int NSH = (TT/64)*(SS/64);   // 256

  if(bid < NSH){
    int n0 = (bid & 31) * 64;
    int r0 = (bid >> 5) * 64;
    f32x4 ag[4]={zero,zero,zero,zero}, au[4]={zero,zero,zero,zero};
    const unsigned short* Ap = xb + (size_t)(r0 + w*16 + n16)*HH + q*8;
    const unsigned short* Gp = Bsg + ((size_t)q*SS + n0 + n16)*8;
    const unsigned short* Up = Bsu + ((size_t)q*SS + n0 + n16)*8;
    gemm_rd<true>(Ap, Gp, Up, SS, HH/32, ag, au);
    int rb = r0 + w*16 + q*4;
    #pragma unroll
    for(int c=0;c<4;c++){
      #pragma unroll
      for(int j=0;j<4;j++){
        float g = ag[c][j], u = au[c][j];
        Hs[(size_t)(rb+j)*SS + n0 + c*16 + n16] = f2bf(g*u/(1.f+__expf(-g)));
      }
    }
  } else {
    int b = bid - NSH;
    int e = b >> 3;            // II/64 = 8 n-tiles per expert
    int i0 = (b & 7) * 64;
    int cnt = counts[e]; if(cnt == 0) return;
    int off = offs[e];
    const unsigned short* Gb = Bgate + (size_t)e*HH*II + ((size_t)q*II + i0 + n16)*8;
    const unsigned short* Ub = Bup   + (size_t)e*HH*II + ((size_t)q*II + i0 + n16)*8;
    for(int rt=0; rt*64<cnt; rt++){
      int nv = cnt - rt*64; if(nv > 64) nv = 64;
      int ra = w*16 + n16; if(ra >= nv) ra = nv-1;
      int rowA = token_list[e*TT + rt*64 + ra];
      f32x4 ag[4]={zero,zero,zero,zero}, au[4]={zero,zero,zero,zero};
      const unsigned short* Ap = xb + (size_t)rowA*HH + q*8;
      gemm_rd<true>(Ap, Gb, Ub, II, HH/32, ag, au);
      int rr0 = w*16 + q*4;
      #pragma unroll
      for(int c=0;c<4;c++){
        #pragma unroll
        for(int j=0;j<4;j++){
          int rr = rr0 + j;
          if(rr < nv){
            float g = ag[c][j], u = au[c][j];
            hbuf[(size_t)(off+rt*64+rr)*II + i0 + c*16 + n16] =
                f2bf(g*u/(1.f+__expf(-g)));
          }
        }
      }
    }
  }
}

// ---------------- phase 3: ALL down (shared + routed), atomic out -----------
__global__ __launch_bounds__(256) void k_down(
    const unsigned short* __restrict__ Hsrc, const unsigned short* __restrict__ Bsd,
    const float* __restrict__ sig_gate,
    const unsigned short* __restrict__ hbuf, const unsigned short* __restrict__ Bdown,
    const int* __restrict__ token_list, const float* __restrict__ weight_list,
    const int* __restrict__ counts, const int* __restrict__ offs,
    float* __restrict__ out){
  int tid = threadIdx.x, w = tid>>6, l = tid&63;
  int n16 = l&15, q = l>>4;
  int bid = blockIdx.x;
  f32x4 zero = {0.f,0.f,0.f,0.f};
  const int NSH = (TT/64)*(HH/64);   // 128

  if(bid < NSH){
    int n0 = (bid & 15) * 64;
    int r0 = (bid >> 4) * 64;
    f32x4 acc[4]={zero,zero,zero,zero};
    const unsigned short* Ap = Hsrc + (size_t)(r0 + w*16 + n16)*SS + q*8;
    const unsigned short* Bp = Bsd + ((size_t)q*HH + n0 + n16)*8;
    gemm_rd<false>(Ap, Bp, Bp, HH, SS/32, acc, acc);
    int rb = r0 + w*16 + q*4;
    #pragma unroll
    for(int c=0;c<4;c++){
      #pragma unroll
      for(int j=0;j<4;j++){
        atomicAdd(&out[(size_t)(rb+j)*HH + n0 + c*16 + n16],
                  sig_gate[rb+j]*acc[c][j]);
      }
    }
  } else {
    int b = bid - NSH;
    int e = b >> 4;            // HH/64 = 16 n-tiles per expert
    int n0 = (b & 15) * 64;
    int cnt = counts[e]; if(cnt == 0) return;
    int off = offs[e];
    const unsigned short* Bb = Bdown + (size_t)e*II*HH + ((size_t)q*HH + n0 + n16)*8;
    for(int rt=0; rt*64<cnt; rt++){
      int nv = cnt - rt*64; if(nv > 64) nv = 64;
      int ra = w*16 + n16; if(ra >= nv) ra = nv-1;
      f32x4 acc[4]={zero,zero,zero,zero};
      const unsigned short* Ap = hbuf + (size_t)(off+rt*64+ra)*II + q*8;
      gemm_rd<false>(Ap, Bb, Bb, HH, II/32, acc, acc);
      int rr0 = w*16 + q*4;
      #pragma unroll
      for(int c=0;c<4;c++){
        #pragma unroll
        for(int j=0;j<4;j++){
          int rr = rr0 + j;
          if(rr < nv){
            int t = token_list[e*TT + rt*64 + rr];
            float wt = weight_list[e*TT + rt*64 + rr];
            atomicAdd(&out[(size_t)t*HH + n0 + c*16 + n16], wt*acc[c][j]);
          }
        }
      }
    }
  }
}

extern "C" void kernel_launch(void* const* d_in, const int* in_sizes, int n_in,
                              void* d_out, int out_size, void* d_ws, size_t ws_size,
                              hipStream_t stream) {
  const float* x     = (const float*)d_in[0];
  const float* Wg    = (const float*)d_in[1];
  const float* Wgate = (const float*)d_in[2];
  const float* Wup   = (const float*)d_in[3];
  const float* Wdown = (const float*)d_in[4];
  const float* Wsg   = (const float*)d_in[5];
  const float* Wsu   = (const float*)d_in[6];
  const float* Wsd   = (const float*)d_in[7];
  float* out = (float*)d_out;

  char* ws = (char*)d_ws;
  unsigned short* xb   = (unsigned short*)ws; ws += (size_t)TT*HH*2;
  unsigned short* Hs   = (unsigned short*)ws; ws += (size_t)TT*SS*2;
  unsigned short* hbuf = (unsigned short*)ws; ws += (size_t)(TT*KK+64)*II*2;
  int*   token_list  = (int*)ws;   ws += (size_t)EE*TT*4;
  float* weight_list = (float*)ws; ws += (size_t)EE*TT*4;
  int*   topk_idx    = (int*)ws;   ws += (size_t)TT*KK*4;
  float* topk_wq     = (float*)ws; ws += (size_t)TT*KK*4;
  int*   counts      = (int*)ws;   ws += 128;
  int*   offsb       = (int*)ws;   ws += 128;
  float* sig_gate    = (float*)ws; ws += (size_t)TT*4;
  // bf16 k8-packed weights (113 MB)
  unsigned short* Bsg   = (unsigned short*)ws; ws += (size_t)HH*SS*2;
  unsigned short* Bsu   = (unsigned short*)ws; ws += (size_t)HH*SS*2;
  unsigned short* Bgate = (unsigned short*)ws; ws += (size_t)EE*HH*II*2;
  unsigned short* Bup   = (unsigned short*)ws; ws += (size_t)EE*HH*II*2;
  unsigned short* Bdown = (unsigned short*)ws; ws += (size_t)EE*II*HH*2;
  unsigned short* Bsd   = (unsigned short*)ws; ws += (size_t)SS*HH*2;

  hipMemsetAsync(d_out, 0, (size_t)TT*HH*4, stream);
  k_router<<<TT, 64, 0, stream>>>(x, Wg, xb, topk_idx, topk_wq, sig_gate);
  k_build<<<EE, 64, 0, stream>>>(topk_idx, topk_wq, token_list, weight_list, counts);
  k_scan<<<1, 64, 0, stream>>>(counts, offsb);
  // convert gate-up weights first (L3-resident for k_gateup)
  k_convert<<<dim3(SS/256, HH/8, 1),  256, 0, stream>>>(Wsg, Bsg, HH, SS);
  k_convert<<<dim3(SS/256, HH/8, 1),  256, 0, stream>>>(Wsu, Bsu, HH, SS);
  k_convert<<<dim3(II/256, HH/8, EE), 256, 0, stream>>>(Wgate, Bgate, HH, II);
  k_convert<<<dim3(II/256, HH/8, EE), 256, 0, stream>>>(Wup, Bup, HH, II);
  k_gateup<<<(TT/64)*(SS/64) + EE*(II/64), 256, 0, stream>>>(
      xb, Bsg, Bsu, Hs, Bgate, Bup, token_list, counts, offsb, hbuf);
  // convert down weights (L3-resident for k_down)
  k_convert<<<dim3(HH/256, II/8, EE), 256, 0, stream>>>(Wdown, Bdown, II, HH);
  k_convert<<<dim3(HH/256, SS/8, 1),  256, 0, stream>>>(Wsd, Bsd, SS, HH);
  k_down<<<(TT/64)*(HH/64) + EE*(HH/64), 256, 0, stream>>>(
      Hs, Bsd, sig_gate, hbuf, Bdown, token_list, weight_list, counts, offsb, out);
}

// Round 9
// 159.048 us; speedup vs baseline: 1.4397x; 1.4397x over previous
//
#include <hip/hip_runtime.h>
#include <hip/hip_bf16.h>

#define TT 512
#define HH 1024
#define EE 32
#define KK 4
#define II 512
#define SS 2048

using f32x4 = __attribute__((ext_vector_type(4))) float;
using s16x8 = __attribute__((ext_vector_type(8))) short;

__device__ __forceinline__ unsigned short f2bf(float f){
  unsigned int u = __builtin_bit_cast(unsigned int, f);
  u += 0x7fffu + ((u >> 16) & 1u);
  return (unsigned short)(u >> 16);
}

typedef __attribute__((address_space(1))) const unsigned GU;
typedef __attribute__((address_space(3))) unsigned LU;
__device__ __forceinline__ void gload16(const void* g, void* l){
  __builtin_amdgcn_global_load_lds((GU*)g, (LU*)l, 16, 0, 0);
}

#define WAITV(N) asm volatile("s_waitcnt vmcnt(" #N ")" ::: "memory")
#define WAITL()  asm volatile("s_waitcnt lgkmcnt(0)" ::: "memory")
#define SBAR()   { __builtin_amdgcn_s_barrier(); __builtin_amdgcn_sched_barrier(0); }

// ---------------- router ----------------------------------------------------
__global__ __launch_bounds__(64) void k_router(
    const float* __restrict__ x, const float* __restrict__ Wg,
    unsigned short* __restrict__ xb, int* __restrict__ topk_idx,
    float* __restrict__ topk_w, float* __restrict__ sig_gate){
  int t = blockIdx.x; int l = threadIdx.x;
  const float* xr = x + (size_t)t * HH;
  #pragma unroll
  for(int i=0;i<HH/64;i++){
    int h = l + 64*i;
    xb[(size_t)t*HH + h] = f2bf(xr[h]);
  }
  float acc0=0.f, acc1=0.f, acc2=0.f, acc3=0.f;
  if(l < EE+1){
    const float* wcol = Wg + l;
    for(int h=0; h<HH; h+=4){
      acc0 += xr[h]   * wcol[(size_t)h*(EE+1)];
      acc1 += xr[h+1] * wcol[(size_t)(h+1)*(EE+1)];
      acc2 += xr[h+2] * wcol[(size_t)(h+2)*(EE+1)];
      acc3 += xr[h+3] * wcol[(size_t)(h+3)*(EE+1)];
    }
  }
  __shared__ float lg[EE+1];
  if(l < EE+1) lg[l] = (acc0+acc1)+(acc2+acc3);
  __syncthreads();
  if(l == 0){
    float v[EE];
    #pragma unroll
    for(int i=0;i<EE;i++) v[i]=lg[i];
    int idx[KK]; float val[KK];
    #pragma unroll
    for(int k=0;k<KK;k++){
      float m=-1e30f; int mi=0;
      for(int i=0;i<EE;i++){ if(v[i]>m){ m=v[i]; mi=i; } }
      idx[k]=mi; val[k]=m; v[mi]=-1e30f;
    }
    float mx = val[0], s=0.f; float w[KK];
    #pragma unroll
    for(int k=0;k<KK;k++){ w[k]=__expf(val[k]-mx); s+=w[k]; }
    float inv = 1.f/s;
    #pragma unroll
    for(int k=0;k<KK;k++){ topk_idx[t*KK+k]=idx[k]; topk_w[t*KK+k]=w[k]*inv; }
    sig_gate[t] = 1.f/(1.f+__expf(-lg[EE]));
  }
}

// ---------------- per-expert token list -------------------------------------
__global__ __launch_bounds__(64) void k_build(
    const int* __restrict__ topk_idx, const float* __restrict__ topk_w,
    int* __restrict__ token_list, float* __restrict__ weight_list,
    int* __restrict__ counts){
  int e = blockIdx.x; int l = threadIdx.x;
  int cnt = 0;
  for(int c=0;c<TT;c+=64){
    int t = c + l;
    int kk = -1;
    #pragma unroll
    for(int k=0;k<KK;k++) if(topk_idx[t*KK+k]==e) kk=k;
    unsigned long long b = __ballot(kk>=0);
    int pre = __popcll(b & ((1ull<<l)-1ull));
    if(kk>=0){
      token_list[e*TT + cnt + pre] = t;
      weight_list[e*TT + cnt + pre] = topk_w[t*KK+kk];
    }
    cnt += __popcll(b);
  }
  if(l==0) counts[e]=cnt;
}

__global__ __launch_bounds__(64) void k_scan(
    const int* __restrict__ counts, int* __restrict__ offs){
  if(threadIdx.x==0){
    int o=0;
    for(int e=0;e<EE;e++){ offs[e]=o; o+=counts[e]; }
  }
}

// ---------- convert fp32 [K][N] -> bf16 k8-packed [K/8][N][8] ---------------
__device__ __forceinline__ void conv_tile(float (*tile)[260],
    const float* __restrict__ S, unsigned short* __restrict__ D,
    int N, int x, int y, int t){
  int k0 = y*8, n0 = x*256;
  int row = t>>5, c8 = (t&31)*8;
  const float* p = S + (size_t)(k0+row)*N + n0 + c8;
  float4 v0 = *reinterpret_cast<const float4*>(p);
  float4 v1 = *reinterpret_cast<const float4*>(p+4);
  *reinterpret_cast<float4*>(&tile[row][c8])   = v0;
  *reinterpret_cast<float4*>(&tile[row][c8+4]) = v1;
  __syncthreads();
  unsigned short u[8];
  #pragma unroll
  for(int r=0;r<8;r++) u[r] = f2bf(tile[r][t]);
  uint4 o;
  o.x = (unsigned)u[0] | ((unsigned)u[1]<<16);
  o.y = (unsigned)u[2] | ((unsigned)u[3]<<16);
  o.z = (unsigned)u[4] | ((unsigned)u[5]<<16);
  o.w = (unsigned)u[6] | ((unsigned)u[7]<<16);
  *reinterpret_cast<uint4*>(D + ((size_t)(k0>>3)*N + n0 + t)*8) = o;
}

// gate/up weight converts: one launch, 18432 blocks
__global__ __launch_bounds__(256) void k_cvt_gu(
    const float* __restrict__ Wsg, unsigned short* __restrict__ Bsg,
    const float* __restrict__ Wsu, unsigned short* __restrict__ Bsu,
    const float* __restrict__ Wgate, unsigned short* __restrict__ Bgate,
    const float* __restrict__ Wup, unsigned short* __restrict__ Bup){
  __shared__ __align__(16) float tile[8][260];
  int bid = blockIdx.x, t = threadIdx.x;
  if(bid < 1024){ conv_tile(tile, Wsg, Bsg, SS, bid&7, bid>>3, t); }
  else if(bid < 2048){ int i=bid-1024; conv_tile(tile, Wsu, Bsu, SS, i&7, i>>3, t); }
  else {
    int i = bid - 2048;
    if(i < 8192){ int e=i>>8, r=i&255;
      conv_tile(tile, Wgate + (size_t)e*HH*II, Bgate + (size_t)e*HH*II, II, r&1, r>>1, t);
    } else { i -= 8192; int e=i>>8, r=i&255;
      conv_tile(tile, Wup + (size_t)e*HH*II, Bup + (size_t)e*HH*II, II, r&1, r>>1, t);
    }
  }
}

// ============ DMA-ring GEMM core: C(128x64) += A(128xK)*B(Kx64) =============
// 4-deep global_load_lds ring, counted vmcnt, K-step 32, 4 waves x 32 rows.
// LDS: A slots 4x8KB (rows 128 x 64B, seg XOR-swizzled via source);
//      B(G) slots 4x4KB at 32768; B(U) slots 4x4KB at 49152.
// Per wave per step: 4 DMA ops (dual) / 3 (single) -> vmcnt(12)/(9) steady.
template<bool DUAL>
__device__ __forceinline__ void gemm_core(
    char* lds, int tid, int NK,
    const char* s0, long a0, unsigned d0, unsigned e0,
    const char* s1, long a1, unsigned d1, unsigned e1,
    const char* s2, long a2, unsigned d2, unsigned e2,
    const char* s3, long a3, unsigned d3, unsigned e3,
    f32x4 (&ag)[2][4], f32x4 (&au)[2][4])
{
  const int l = tid&63, w = tid>>6;
  const int mm = l&15, kt = l>>4;
  const int r0l = w*32 + mm, r1l = r0l + 16;
  const unsigned aof0 = (unsigned)(r0l*64 + ((kt ^ ((r0l>>1)&3))<<4));
  const unsigned aof1 = (unsigned)(r1l*64 + ((kt ^ ((r1l>>1)&3))<<4));
  const unsigned bof  = (unsigned)(32768 + kt*1024 + (mm<<4));

#define ISS(ks_) { const int sl_=(ks_)&3;                                   \
    gload16(s0+(long)(ks_)*a0, lds + d0 + sl_*e0);                          \
    gload16(s1+(long)(ks_)*a1, lds + d1 + sl_*e1);                          \
    gload16(s2+(long)(ks_)*a2, lds + d2 + sl_*e2);                          \
    if(DUAL){ gload16(s3+(long)(ks_)*a3, lds + d3 + sl_*e3); } }

#define COMP(ks_) { const int sl_=(ks_)&3;                                  \
    const char* Ab = lds + sl_*8192;                                        \
    s16x8 af0 = *reinterpret_cast<const s16x8*>(Ab + aof0);                 \
    s16x8 af1 = *reinterpret_cast<const s16x8*>(Ab + aof1);                 \
    const char* Bb = lds + sl_*4096;                                        \
    _Pragma("unroll")                                                       \
    for(int c=0;c<4;c++){                                                   \
      s16x8 bg = *reinterpret_cast<const s16x8*>(Bb + bof + c*256);         \
      ag[0][c] = __builtin_amdgcn_mfma_f32_16x16x32_bf16(af0, bg, ag[0][c],0,0,0); \
      ag[1][c] = __builtin_amdgcn_mfma_f32_16x16x32_bf16(af1, bg, ag[1][c],0,0,0); \
      if(DUAL){                                                             \
        s16x8 bu = *reinterpret_cast<const s16x8*>(Bb + bof + 16384 + c*256); \
        au[0][c] = __builtin_amdgcn_mfma_f32_16x16x32_bf16(af0, bu, au[0][c],0,0,0); \
        au[1][c] = __builtin_amdgcn_mfma_f32_16x16x32_bf16(af1, bu, au[1][c],0,0,0); } } }

  ISS(0); ISS(1); ISS(2); ISS(3);
  int ks = 0;
  for(; ks < NK-3; ks++){
    if constexpr(DUAL){ WAITV(12); } else { WAITV(9); }
    SBAR();
    COMP(ks);
    WAITL(); SBAR();
    ISS(ks+4);
  }
  if constexpr(DUAL){ WAITV(8); } else { WAITV(6); }
  SBAR(); COMP(ks); WAITL(); SBAR(); ks++;
  if constexpr(DUAL){ WAITV(4); } else { WAITV(3); }
  SBAR(); COMP(ks); WAITL(); SBAR(); ks++;
  WAITV(0);
  SBAR(); COMP(ks); WAITL(); SBAR();
#undef ISS
#undef COMP
}

// op setup: dual 16 ops (0-7 A, 8-11 G, 12-15 U); single 12 ops (0-7 A, 8-11 B)
#define MK_GU(o_, sv, av, dv, ev, ABEXPR)                                   \
  { const int oo_ = (o_);                                                   \
    if(oo_ < 8){                                                            \
      const int rl_ = oo_*16 + (l>>2);                                      \
      const int sg_ = (l&3) ^ ((rl_>>1)&3);                                 \
      sv = (ABEXPR) + sg_*16;                                               \
      av = 64; dv = (unsigned)(oo_*1024); ev = 8192;                        \
    } else if(oo_ < 12){ const int q_ = oo_-8;                              \
      sv = (const char*)Gb + ((size_t)q_*Nb + (size_t)n0w + l)*16;          \
      av = (long)Nb*64; dv = (unsigned)(32768 + q_*1024); ev = 4096;        \
    } else { const int q_ = oo_-12;                                         \
      sv = (const char*)Ub + ((size_t)q_*Nb + (size_t)n0w + l)*16;          \
      av = (long)Nb*64; dv = (unsigned)(49152 + q_*1024); ev = 4096; } }

#define MK_S(o_, sv, av, dv, ev, ABEXPR)                                    \
  { const int oo_ = (o_);                                                   \
    if(oo_ < 8){                                                            \
      const int rl_ = oo_*16 + (l>>2);                                      \
      const int sg_ = (l&3) ^ ((rl_>>1)&3);                                 \
      sv = (ABEXPR) + sg_*16;                                               \
      av = 64; dv = (unsigned)(oo_*1024); ev = 8192;                        \
    } else { const int q_ = oo_-8;                                          \
      sv = (const char*)Bb0 + ((size_t)(kq0 + q_)*Nb + (size_t)n0w + l)*16; \
      av = (long)Nb*64; dv = (unsigned)(32768 + q_*1024); ev = 4096; } }

// ---------------- gateup (384 gemm blocks) + down-weight converts (9216) ----
__global__ __launch_bounds__(256) void k_gateup_cvt(
    const unsigned short* __restrict__ xb,
    const unsigned short* __restrict__ Bsg, const unsigned short* __restrict__ Bsu,
    unsigned short* __restrict__ Hs,
    const unsigned short* __restrict__ Bgate, const unsigned short* __restrict__ Bup,
    const int* __restrict__ token_list, const int* __restrict__ counts,
    const int* __restrict__ offs, unsigned short* __restrict__ hbuf,
    const float* __restrict__ Wdown, unsigned short* __restrict__ Bdown,
    const float* __restrict__ Wsd, unsigned short* __restrict__ Bsd){
  __shared__ __align__(16) char lds[65536];
  int bid = blockIdx.x, tid = threadIdx.x;
  if(bid >= 384){
    int cb = bid - 384;
    float (*tile)[260] = (float(*)[260])lds;
    if(cb < 8192){ int e=cb>>8, r=cb&255;
      conv_tile(tile, Wdown + (size_t)e*II*HH, Bdown + (size_t)e*II*HH, HH, r&3, r>>2, tid);
    } else { int j=cb-8192;
      conv_tile(tile, Wsd, Bsd, HH, j&3, j>>2, tid);
    }
    return;
  }
  const int w = tid>>6, l = tid&63;
  const int mm = l&15, kt = l>>4;
  f32x4 zero = {0.f,0.f,0.f,0.f};
  f32x4 ag[2][4], au[2][4];

  if(bid < 128){
    // shared gate-up: r0 = rb*128, n0 = nb*64
    int r0 = (bid>>5)*128, n0 = (bid&31)*64;
    const unsigned short* Gb = Bsg; const unsigned short* Ub = Bsu;
    int Nb = SS, n0w = n0;
    #pragma unroll
    for(int mf=0;mf<2;mf++)
      #pragma unroll
      for(int c=0;c<4;c++){ ag[mf][c]=zero; au[mf][c]=zero; }
    const char *s0,*s1,*s2,*s3; long a0,a1,a2,a3; unsigned d0,d1,d2,d3,e0,e1,e2,e3;
    MK_GU(w*4+0, s0,a0,d0,e0, (const char*)xb + (size_t)(r0+rl_)*(HH*2))
    MK_GU(w*4+1, s1,a1,d1,e1, (const char*)xb + (size_t)(r0+rl_)*(HH*2))
    MK_GU(w*4+2, s2,a2,d2,e2, (const char*)xb + (size_t)(r0+rl_)*(HH*2))
    MK_GU(w*4+3, s3,a3,d3,e3, (const char*)xb + (size_t)(r0+rl_)*(HH*2))
    gemm_core<true>(lds, tid, HH/32, s0,a0,d0,e0, s1,a1,d1,e1, s2,a2,d2,e2, s3,a3,d3,e3, ag, au);
    #pragma unroll
    for(int mf=0;mf<2;mf++){
      #pragma unroll
      for(int c=0;c<4;c++){
        #pragma unroll
        for(int j=0;j<4;j++){
          int lrow = w*32 + mf*16 + kt*4 + j;
          float gg = ag[mf][c][j], uu = au[mf][c][j];
          Hs[(size_t)(r0+lrow)*SS + n0 + c*16 + mm] = f2bf(gg*uu/(1.f+__expf(-gg)));
        }
      }
    }
  } else {
    // expert gate-up: e, i0
    int g = bid - 128;
    int e = g>>3, i0 = (g&7)*64;
    int cnt = counts[e]; if(cnt == 0) return;
    int off = offs[e];
    const unsigned short* Gb = Bgate + (size_t)e*HH*II;
    const unsigned short* Ub = Bup   + (size_t)e*HH*II;
    int Nb = II, n0w = i0;
    for(int rt=0; rt*128<cnt; rt++){
      int nv = cnt - rt*128; if(nv > 128) nv = 128;
      WAITV(0);
      #pragma unroll
      for(int mf=0;mf<2;mf++)
        #pragma unroll
        for(int c=0;c<4;c++){ ag[mf][c]=zero; au[mf][c]=zero; }
      const char *s0,*s1,*s2,*s3; long a0,a1,a2,a3; unsigned d0,d1,d2,d3,e0,e1,e2,e3;
      MK_GU(w*4+0, s0,a0,d0,e0, (const char*)xb + (size_t)token_list[e*TT + rt*128 + (rl_<nv?rl_:nv-1)]*(HH*2))
      MK_GU(w*4+1, s1,a1,d1,e1, (const char*)xb + (size_t)token_list[e*TT + rt*128 + (rl_<nv?rl_:nv-1)]*(HH*2))
      MK_GU(w*4+2, s2,a2,d2,e2, (const char*)xb + (size_t)token_list[e*TT + rt*128 + (rl_<nv?rl_:nv-1)]*(HH*2))
      MK_GU(w*4+3, s3,a3,d3,e3, (const char*)xb + (size_t)token_list[e*TT + rt*128 + (rl_<nv?rl_:nv-1)]*(HH*2))
      gemm_core<true>(lds, tid, HH/32, s0,a0,d0,e0, s1,a1,d1,e1, s2,a2,d2,e2, s3,a3,d3,e3, ag, au);
      #pragma unroll
      for(int mf=0;mf<2;mf++){
        #pragma unroll
        for(int c=0;c<4;c++){
          #pragma unroll
          for(int j=0;j<4;j++){
            int lrow = w*32 + mf*16 + kt*4 + j;
            if(lrow < nv){
              float gg = ag[mf][c][j], uu = au[mf][c][j];
              hbuf[(size_t)(off+rt*128+lrow)*II + i0 + c*16 + mm] =
                  f2bf(gg*uu/(1.f+__expf(-gg)));
            }
          }
        }
      }
    }
  }
}

// ---------------- down: shared (split-K x4) + expert, atomic out ------------
__global__ __launch_bounds__(256) void k_down(
    const unsigned short* __restrict__ Hs, const unsigned short* __restrict__ Bsd,
    const float* __restrict__ sig_gate,
    const unsigned short* __restrict__ hbuf, const unsigned short* __restrict__ Bdown,
    const int* __restrict__ token_list, const float* __restrict__ weight_list,
    const int* __restrict__ counts, const int* __restrict__ offs,
    float* __restrict__ out){
  __shared__ __align__(16) char lds[49152];
  int bid = blockIdx.x, tid = threadIdx.x;
  const int w = tid>>6, l = tid&63;
  const int mm = l&15, kt = l>>4;
  f32x4 zero = {0.f,0.f,0.f,0.f};
  f32x4 ag[2][4], au[2][4];  // au unused (single)

  if(bid < 256){
    // shared down: rb, nb, kc
    int rb = bid>>6, rem = bid&63;
    int nb = rem>>2, kc = rem&3;
    int r0 = rb*128, n0 = nb*64;
    const unsigned short* Bb0 = Bsd;
    int Nb = HH, n0w = n0, kq0 = kc*64;
    #pragma unroll
    for(int mf=0;mf<2;mf++)
      #pragma unroll
      for(int c=0;c<4;c++){ ag[mf][c]=zero; au[mf][c]=zero; }
    const char *s0,*s1,*s2; long a0,a1,a2; unsigned d0,d1,d2,e0,e1,e2;
    MK_S(w*3+0, s0,a0,d0,e0, (const char*)Hs + (size_t)(r0+rl_)*(SS*2) + kc*1024)
    MK_S(w*3+1, s1,a1,d1,e1, (const char*)Hs + (size_t)(r0+rl_)*(SS*2) + kc*1024)
    MK_S(w*3+2, s2,a2,d2,e2, (const char*)Hs + (size_t)(r0+rl_)*(SS*2) + kc*1024)
    gemm_core<false>(lds, tid, 16, s0,a0,d0,e0, s1,a1,d1,e1, s2,a2,d2,e2, s0,0,0,0, ag, au);
    #pragma unroll
    for(int mf=0;mf<2;mf++){
      #pragma unroll
      for(int c=0;c<4;c++){
        #pragma unroll
        for(int j=0;j<4;j++){
          int lrow = w*32 + mf*16 + kt*4 + j;
          atomicAdd(&out[(size_t)(r0+lrow)*HH + n0 + c*16 + mm],
                    sig_gate[r0+lrow]*ag[mf][c][j]);
        }
      }
    }
  } else {
    // expert down
    int b = bid - 256;
    int e = b>>4, n0 = (b&15)*64;
    int cnt = counts[e]; if(cnt == 0) return;
    int off = offs[e];
    const unsigned short* Bb0 = Bdown + (size_t)e*II*HH;
    int Nb = HH, n0w = n0, kq0 = 0;
    for(int rt=0; rt*128<cnt; rt++){
      int nv = cnt - rt*128; if(nv > 128) nv = 128;
      WAITV(0);
      #pragma unroll
      for(int mf=0;mf<2;mf++)
        #pragma unroll
        for(int c=0;c<4;c++){ ag[mf][c]=zero; au[mf][c]=zero; }
      const char *s0,*s1,*s2; long a0,a1,a2; unsigned d0,d1,d2,e0,e1,e2;
      MK_S(w*3+0, s0,a0,d0,e0, (const char*)hbuf + (size_t)(off + rt*128 + (rl_<nv?rl_:nv-1))*(II*2))
      MK_S(w*3+1, s1,a1,d1,e1, (const char*)hbuf + (size_t)(off + rt*128 + (rl_<nv?rl_:nv-1))*(II*2))
      MK_S(w*3+2, s2,a2,d2,e2, (const char*)hbuf + (size_t)(off + rt*128 + (rl_<nv?rl_:nv-1))*(II*2))
      gemm_core<false>(lds, tid, 16, s0,a0,d0,e0, s1,a1,d1,e1, s2,a2,d2,e2, s0,0,0,0, ag, au);
      #pragma unroll
      for(int mf=0;mf<2;mf++){
        #pragma unroll
        for(int c=0;c<4;c++){
          #pragma unroll
          for(int j=0;j<4;j++){
            int lrow = w*32 + mf*16 + kt*4 + j;
            if(lrow < nv){
              int t = token_list[e*TT + rt*128 + lrow];
              float wt = weight_list[e*TT + rt*128 + lrow];
              atomicAdd(&out[(size_t)t*HH + n0 + c*16 + mm], wt*ag[mf][c][j]);
            }
          }
        }
      }
    }
  }
}

extern "C" void kernel_launch(void* const* d_in, const int* in_sizes, int n_in,
                              void* d_out, int out_size, void* d_ws, size_t ws_size,
                              hipStream_t stream) {
  const float* x     = (const float*)d_in[0];
  const float* Wg    = (const float*)d_in[1];
  const float* Wgate = (const float*)d_in[2];
  const float* Wup   = (const float*)d_in[3];
  const float* Wdown = (const float*)d_in[4];
  const float* Wsg   = (const float*)d_in[5];
  const float* Wsu   = (const float*)d_in[6];
  const float* Wsd   = (const float*)d_in[7];
  float* out = (float*)d_out;

  char* ws = (char*)d_ws;
  unsigned short* xb   = (unsigned short*)ws; ws += (size_t)TT*HH*2;
  unsigned short* Hs   = (unsigned short*)ws; ws += (size_t)TT*SS*2;
  unsigned short* hbuf = (unsigned short*)ws; ws += (size_t)(TT*KK+128)*II*2;
  int*   token_list  = (int*)ws;   ws += (size_t)EE*TT*4;
  float* weight_list = (float*)ws; ws += (size_t)EE*TT*4;
  int*   topk_idx    = (int*)ws;   ws += (size_t)TT*KK*4;
  float* topk_wq     = (float*)ws; ws += (size_t)TT*KK*4;
  int*   counts      = (int*)ws;   ws += 128;
  int*   offsb       = (int*)ws;   ws += 128;
  float* sig_gate    = (float*)ws; ws += (size_t)TT*4;
  unsigned short* Bsg   = (unsigned short*)ws; ws += (size_t)HH*SS*2;
  unsigned short* Bsu   = (unsigned short*)ws; ws += (size_t)HH*SS*2;
  unsigned short* Bgate = (unsigned short*)ws; ws += (size_t)EE*HH*II*2;
  unsigned short* Bup   = (unsigned short*)ws; ws += (size_t)EE*HH*II*2;
  unsigned short* Bdown = (unsigned short*)ws; ws += (size_t)EE*II*HH*2;
  unsigned short* Bsd   = (unsigned short*)ws; ws += (size_t)SS*HH*2;

  hipMemsetAsync(d_out, 0, (size_t)TT*HH*4, stream);
  k_router<<<TT, 64, 0, stream>>>(x, Wg, xb, topk_idx, topk_wq, sig_gate);
  k_build<<<EE, 64, 0, stream>>>(topk_idx, topk_wq, token_list, weight_list, counts);
  k_scan<<<1, 64, 0, stream>>>(counts, offsb);
  k_cvt_gu<<<18432, 256, 0, stream>>>(Wsg, Bsg, Wsu, Bsu, Wgate, Bgate, Wup, Bup);
  k_gateup_cvt<<<384 + 9216, 256, 0, stream>>>(
      xb, Bsg, Bsu, Hs, Bgate, Bup, token_list, counts, offsb, hbuf,
      Wdown, Bdown, Wsd, Bsd);
  k_down<<<256 + EE*(HH/64), 256, 0, stream>>>(
      Hs, Bsd, sig_gate, hbuf, Bdown, token_list, weight_list, counts, offsb, out);
}